// Round 1
// baseline (8997.005 us; speedup 1.0000x reference)
//
#include <hip/hip_runtime.h>
#include <hip/hip_bf16.h>
#include <math.h>

#define Lh 2304
#define Ch 768
#define NHh 12
#define Bh 2

// ---------------------------------------------------------------- layernorm
__global__ __launch_bounds__(256)
void layernorm_kernel(const float* __restrict__ x, const float* __restrict__ w,
                      const float* __restrict__ b, float* __restrict__ y)
{
    int row = blockIdx.x;
    int tid = threadIdx.x;
    const float* xr = x + (size_t)row * Ch;
    float v0 = xr[tid], v1 = xr[tid + 256], v2 = xr[tid + 512];
    __shared__ float red[256];
    red[tid] = v0 + v1 + v2;
    __syncthreads();
    for (int st = 128; st > 0; st >>= 1) {
        if (tid < st) red[tid] += red[tid + st];
        __syncthreads();
    }
    float mean = red[0] * (1.0f / 768.0f);
    __syncthreads();
    float d0 = v0 - mean, d1 = v1 - mean, d2 = v2 - mean;
    red[tid] = d0 * d0 + d1 * d1 + d2 * d2;
    __syncthreads();
    for (int st = 128; st > 0; st >>= 1) {
        if (tid < st) red[tid] += red[tid + st];
        __syncthreads();
    }
    float rstd = rsqrtf(red[0] * (1.0f / 768.0f) + 1e-6f);
    float* yr = y + (size_t)row * Ch;
    yr[tid]       = d0 * rstd * w[tid]       + b[tid];
    yr[tid + 256] = d1 * rstd * w[tid + 256] + b[tid + 256];
    yr[tid + 512] = d2 * rstd * w[tid + 512] + b[tid + 512];
}

// ---------------------------------------------------------------- mask pooling
__global__ __launch_bounds__(256)
void mask_pool_kernel(const float* __restrict__ mask, float* __restrict__ fg)
{
    int idx = blockIdx.x * 256 + threadIdx.x;   // over B*48*48 = 4608
    if (idx >= Bh * 48 * 48) return;
    int b = idx / (48 * 48);
    int rem = idx % (48 * 48);
    int i = rem / 48, j = rem % 48;
    const float* mb = mask + (size_t)b * 192 * 192;
    float s = 0.0f;
    #pragma unroll
    for (int di = 0; di < 4; ++di)
        #pragma unroll
        for (int dj = 0; dj < 4; ++dj)
            s += mb[(i * 4 + di) * 192 + (j * 4 + dj)];
    fg[idx] = (s * (1.0f / 16.0f) > 0.4f) ? 1.0f : 0.0f;
}

__global__ __launch_bounds__(256)
void mask_win_kernel(const float* __restrict__ fg, float* __restrict__ bgw)
{
    int idx = blockIdx.x * 256 + threadIdx.x;   // over B*6*6 = 72 windows
    if (idx >= Bh * 36) return;
    int b = idx / 36, rem = idx % 36;
    int wi = rem / 6, wj = rem % 6;
    float anybg = 0.0f;
    for (int r = 0; r < 8; ++r)
        for (int c = 0; c < 8; ++c) {
            int n = (wi * 8 + r) * 48 + wj * 8 + c;
            if (fg[b * Lh + n] == 0.0f) anybg = 1.0f;
        }
    bgw[idx] = anybg;
}

// ---------------------------------------------------------------- GEMM
// C[M,N] = act(A[M,K] @ B[K,N] + bias[N]) (+ residual)
#define BM 64
#define BN 64
#define BK 16

__global__ __launch_bounds__(256)
void gemm_kernel(const float* __restrict__ A, const float* __restrict__ B,
                 const float* __restrict__ bias, const float* __restrict__ residual,
                 float* __restrict__ C, int M, int N, int K, int gelu)
{
    __shared__ float As[BK][BM + 4];
    __shared__ float Bs[BK][BN + 4];
    int bm = blockIdx.y * BM;
    int bn = blockIdx.x * BN;
    int tid = threadIdx.x;
    int tx = tid % 16;   // col group
    int ty = tid / 16;   // row group
    float acc[4][4] = {{0.f}};

    for (int k0 = 0; k0 < K; k0 += BK) {
        #pragma unroll
        for (int i = 0; i < 4; ++i) {
            int e = tid + i * 256;
            int m = e / BK, kk = e % BK;
            As[kk][m] = A[(size_t)(bm + m) * K + k0 + kk];
        }
        #pragma unroll
        for (int i = 0; i < 4; ++i) {
            int e = tid + i * 256;
            int kk = e / BN, n = e % BN;
            Bs[kk][n] = B[(size_t)(k0 + kk) * N + bn + n];
        }
        __syncthreads();
        #pragma unroll
        for (int kk = 0; kk < BK; ++kk) {
            float4 a = *(const float4*)&As[kk][ty * 4];
            float4 b4 = *(const float4*)&Bs[kk][tx * 4];
            float av[4] = {a.x, a.y, a.z, a.w};
            float bv[4] = {b4.x, b4.y, b4.z, b4.w};
            #pragma unroll
            for (int i = 0; i < 4; ++i)
                #pragma unroll
                for (int j = 0; j < 4; ++j)
                    acc[i][j] += av[i] * bv[j];
        }
        __syncthreads();
    }

    #pragma unroll
    for (int i = 0; i < 4; ++i) {
        int m = bm + ty * 4 + i;
        float4 out;
        float* o = (float*)&out;
        #pragma unroll
        for (int j = 0; j < 4; ++j) {
            int n = bn + tx * 4 + j;
            float v = acc[i][j] + bias[n];
            if (gelu) v = v * 0.5f * (1.0f + erff(v * 0.70710678f));
            if (residual) v += residual[(size_t)m * N + n];
            o[j] = v;
        }
        *(float4*)&C[(size_t)m * N + bn + tx * 4] = out;
    }
}

// ---------------------------------------------------------------- global attention
// wave per (b, h, q); lanes split 2304 keys (36 each)
__global__ __launch_bounds__(256)
void attn_global_kernel(const float* __restrict__ Q, const float* __restrict__ K,
                        const float* __restrict__ V, const float* __restrict__ fg,
                        float* __restrict__ O)
{
    int gwave = (blockIdx.x * 256 + threadIdx.x) >> 6;
    int lane = threadIdx.x & 63;
    int wid = threadIdx.x >> 6;
    int q = gwave % Lh;
    int bh = gwave / Lh;
    int h = bh % NHh, b = bh / NHh;

    __shared__ float qs[4][64];
    qs[wid][lane] = Q[(size_t)(b * Lh + q) * Ch + h * 64 + lane];
    __syncthreads();
    float4 qv[16];
    #pragma unroll
    for (int i = 0; i < 16; ++i) qv[i] = *(const float4*)&qs[wid][i * 4];

    float dots[36];
    float mymax = -1e30f;
    #pragma unroll
    for (int t = 0; t < 36; ++t) {
        int kk = lane + t * 64;
        const float4* krow = (const float4*)(K + (size_t)(b * Lh + kk) * Ch + h * 64);
        float d = 0.0f;
        #pragma unroll
        for (int i = 0; i < 16; ++i) {
            float4 kv = krow[i];
            d += qv[i].x * kv.x + qv[i].y * kv.y + qv[i].z * kv.z + qv[i].w * kv.w;
        }
        d *= 0.125f;
        if (fg[b * Lh + kk] == 0.0f) d = -1e9f;
        dots[t] = d;
        mymax = fmaxf(mymax, d);
    }
    #pragma unroll
    for (int off = 32; off >= 1; off >>= 1)
        mymax = fmaxf(mymax, __shfl_xor(mymax, off, 64));

    float lsum = 0.0f;
    #pragma unroll
    for (int t = 0; t < 36; ++t) {
        float p = __expf(dots[t] - mymax);
        dots[t] = p;
        lsum += p;
    }
    #pragma unroll
    for (int off = 32; off >= 1; off >>= 1)
        lsum += __shfl_xor(lsum, off, 64);

    float4 acc[16];
    #pragma unroll
    for (int i = 0; i < 16; ++i) acc[i] = make_float4(0.f, 0.f, 0.f, 0.f);
    #pragma unroll
    for (int t = 0; t < 36; ++t) {
        int kk = lane + t * 64;
        const float4* vrow = (const float4*)(V + (size_t)(b * Lh + kk) * Ch + h * 64);
        float p = dots[t];
        #pragma unroll
        for (int i = 0; i < 16; ++i) {
            float4 vv = vrow[i];
            acc[i].x += p * vv.x; acc[i].y += p * vv.y;
            acc[i].z += p * vv.z; acc[i].w += p * vv.w;
        }
    }
    // cross-lane transpose sum: out[d] = sum over lanes of acc[d]
    float res = 0.0f;
    const float* accf = (const float*)acc;
    #pragma unroll
    for (int dd = 0; dd < 64; ++dd) {
        float v = accf[dd];
        #pragma unroll
        for (int off = 32; off >= 1; off >>= 1)
            v += __shfl_xor(v, off, 64);
        if (lane == dd) res = v;
    }
    O[(size_t)(b * Lh + q) * Ch + h * 64 + lane] = res / lsum;
}

// ---------------------------------------------------------------- local windowed attention
// wave per (window, h, q); lane = key within window. Output scattered to token layout.
__global__ __launch_bounds__(256)
void attn_local_kernel(const float* __restrict__ Q, const float* __restrict__ K,
                       const float* __restrict__ V, float* __restrict__ O)
{
    int gwave = (blockIdx.x * 256 + threadIdx.x) >> 6;
    int lane = threadIdx.x & 63;
    int wid = threadIdx.x >> 6;
    int qi = gwave & 63;
    int rest = gwave >> 6;
    int h = rest % NHh;
    int win = rest / NHh;           // 0..71
    int b = win / 36;
    int wrem = win % 36;
    int wi = wrem / 6, wj = wrem % 6;
    int qn = (wi * 8 + (qi >> 3)) * 48 + (wj * 8 + (qi & 7));
    int kn = (wi * 8 + (lane >> 3)) * 48 + (wj * 8 + (lane & 7));

    __shared__ float qs[4][64];
    qs[wid][lane] = Q[(size_t)(b * Lh + qn) * Ch + h * 64 + lane];
    __syncthreads();

    const float4* krow = (const float4*)(K + (size_t)(b * Lh + kn) * Ch + h * 64);
    float d = 0.0f;
    #pragma unroll
    for (int i = 0; i < 16; ++i) {
        float4 kv = krow[i];
        float4 qv = *(const float4*)&qs[wid][i * 4];
        d += qv.x * kv.x + qv.y * kv.y + qv.z * kv.z + qv.w * kv.w;
    }
    d *= 0.125f;
    float m = d;
    #pragma unroll
    for (int off = 32; off >= 1; off >>= 1)
        m = fmaxf(m, __shfl_xor(m, off, 64));
    float p = __expf(d - m);
    float lsum = p;
    #pragma unroll
    for (int off = 32; off >= 1; off >>= 1)
        lsum += __shfl_xor(lsum, off, 64);

    const float4* vrow = (const float4*)(V + (size_t)(b * Lh + kn) * Ch + h * 64);
    float res = 0.0f;
    #pragma unroll
    for (int i = 0; i < 16; ++i) {
        float4 vv = vrow[i];
        float t0 = p * vv.x, t1 = p * vv.y, t2 = p * vv.z, t3 = p * vv.w;
        #pragma unroll
        for (int off = 32; off >= 1; off >>= 1) {
            t0 += __shfl_xor(t0, off, 64);
            t1 += __shfl_xor(t1, off, 64);
            t2 += __shfl_xor(t2, off, 64);
            t3 += __shfl_xor(t3, off, 64);
        }
        if (lane == i * 4 + 0) res = t0;
        if (lane == i * 4 + 1) res = t1;
        if (lane == i * 4 + 2) res = t2;
        if (lane == i * 4 + 3) res = t3;
    }
    O[(size_t)(b * Lh + qn) * Ch + h * 64 + lane] = res / lsum;
}

// ---------------------------------------------------------------- scatter + residual
__global__ __launch_bounds__(256)
void scatter_kernel(const float* __restrict__ x, const float* __restrict__ gout,
                    const float* __restrict__ lout, const float* __restrict__ fg,
                    const float* __restrict__ bgw, float* __restrict__ x1)
{
    int idx = blockIdx.x * 256 + threadIdx.x;   // over B*L*C/4 float4s
    if (idx >= Bh * Lh * Ch / 4) return;
    int token = idx / (Ch / 4);
    int b = token / Lh, n = token % Lh;
    int i = n / 48, j = n % 48;
    int win = b * 36 + (i / 8) * 6 + (j / 8);
    float4 xv = ((const float4*)x)[idx];
    float4 sel;
    if (fg[token] != 0.0f)          sel = ((const float4*)gout)[idx];
    else if (bgw[win] != 0.0f)      sel = ((const float4*)lout)[idx];
    else                            sel = make_float4(0.f, 0.f, 0.f, 0.f);
    float4 out;
    out.x = xv.x + sel.x; out.y = xv.y + sel.y;
    out.z = xv.z + sel.z; out.w = xv.w + sel.w;
    ((float4*)x1)[idx] = out;
}

// ---------------------------------------------------------------- launch
extern "C" void kernel_launch(void* const* d_in, const int* in_sizes, int n_in,
                              void* d_out, int out_size, void* d_ws, size_t ws_size,
                              hipStream_t stream)
{
    const float* x       = (const float*)d_in[0];
    const float* mask    = (const float*)d_in[1];
    const float* w_qkv_g = (const float*)d_in[2];
    const float* b_qkv_g = (const float*)d_in[3];
    const float* w_o_g   = (const float*)d_in[4];
    const float* b_o_g   = (const float*)d_in[5];
    const float* w_qkv_l = (const float*)d_in[6];
    const float* b_qkv_l = (const float*)d_in[7];
    const float* w_o_l   = (const float*)d_in[8];
    const float* b_o_l   = (const float*)d_in[9];
    const float* ln1_w   = (const float*)d_in[10];
    const float* ln1_b   = (const float*)d_in[11];
    const float* ln2_w   = (const float*)d_in[12];
    const float* ln2_b   = (const float*)d_in[13];
    const float* w_fc1   = (const float*)d_in[14];
    const float* b_fc1   = (const float*)d_in[15];
    const float* w_fc2   = (const float*)d_in[16];
    const float* b_fc2   = (const float*)d_in[17];
    float* out = (float*)d_out;

    const size_t U = (size_t)Bh * Lh * Ch;   // 3,538,944 floats
    float* ws   = (float*)d_ws;
    float* xn   = ws;            // U   (reused as h1 after LN2)
    float* qkv  = ws + U;        // 3U  (q,k,v; reused for mid together with ctx)
    float* ctx  = ws + 4 * U;    // U
    float* gout = ws + 5 * U;    // U
    float* lout = ws + 6 * U;    // U
    float* x1   = ws + 7 * U;    // U
    float* fg   = ws + 8 * U;    // 4608
    float* bgw  = fg + Bh * Lh;  // 72
    float* mid  = qkv;           // 4608*3072 = 4U, spans qkv+ctx

    const int Mrows = Bh * Lh;   // 4608
    dim3 blk(256);

    // LN1
    layernorm_kernel<<<Mrows, blk, 0, stream>>>(x, ln1_w, ln1_b, xn);
    // masks
    mask_pool_kernel<<<(Bh * 48 * 48 + 255) / 256, blk, 0, stream>>>(mask, fg);
    mask_win_kernel<<<1, blk, 0, stream>>>(fg, bgw);

    // QKV (global)
    for (int t = 0; t < 3; ++t)
        gemm_kernel<<<dim3(Ch / BN, Mrows / BM), blk, 0, stream>>>(
            xn, w_qkv_g + (size_t)t * Ch * Ch, b_qkv_g + t * Ch, nullptr,
            qkv + t * U, Mrows, Ch, Ch, 0);
    // global attention
    attn_global_kernel<<<(Bh * NHh * Lh) / 4, blk, 0, stream>>>(
        qkv, qkv + U, qkv + 2 * U, fg, ctx);
    gemm_kernel<<<dim3(Ch / BN, Mrows / BM), blk, 0, stream>>>(
        ctx, w_o_g, b_o_g, nullptr, gout, Mrows, Ch, Ch, 0);

    // QKV (local) — reuse qkv buffers
    for (int t = 0; t < 3; ++t)
        gemm_kernel<<<dim3(Ch / BN, Mrows / BM), blk, 0, stream>>>(
            xn, w_qkv_l + (size_t)t * Ch * Ch, b_qkv_l + t * Ch, nullptr,
            qkv + t * U, Mrows, Ch, Ch, 0);
    // local attention
    attn_local_kernel<<<(Bh * 36 * NHh * 64) / 4, blk, 0, stream>>>(
        qkv, qkv + U, qkv + 2 * U, ctx);
    gemm_kernel<<<dim3(Ch / BN, Mrows / BM), blk, 0, stream>>>(
        ctx, w_o_l, b_o_l, nullptr, lout, Mrows, Ch, Ch, 0);

    // scatter + residual -> x1
    scatter_kernel<<<(Bh * Lh * Ch / 4 + 255) / 256, blk, 0, stream>>>(
        x, gout, lout, fg, bgw, x1);

    // LN2 -> h (reuse xn)
    layernorm_kernel<<<Mrows, blk, 0, stream>>>(x1, ln2_w, ln2_b, xn);

    // MLP
    gemm_kernel<<<dim3(3072 / BN, Mrows / BM), blk, 0, stream>>>(
        xn, w_fc1, b_fc1, nullptr, mid, Mrows, 3072, Ch, 1);
    gemm_kernel<<<dim3(Ch / BN, Mrows / BM), blk, 0, stream>>>(
        mid, w_fc2, b_fc2, x1, out, Mrows, Ch, 3072, 0);
}

// Round 2
// 3678.394 us; speedup vs baseline: 2.4459x; 2.4459x over previous
//
#include <hip/hip_runtime.h>
#include <hip/hip_bf16.h>
#include <math.h>

#define Lh 2304
#define Ch 768
#define NHh 12
#define Bh 2

// ---------------------------------------------------------------- layernorm
__global__ __launch_bounds__(256)
void layernorm_kernel(const float* __restrict__ x, const float* __restrict__ w,
                      const float* __restrict__ b, float* __restrict__ y)
{
    int row = blockIdx.x;
    int tid = threadIdx.x;
    const float* xr = x + (size_t)row * Ch;
    float v0 = xr[tid], v1 = xr[tid + 256], v2 = xr[tid + 512];
    __shared__ float red[256];
    red[tid] = v0 + v1 + v2;
    __syncthreads();
    for (int st = 128; st > 0; st >>= 1) {
        if (tid < st) red[tid] += red[tid + st];
        __syncthreads();
    }
    float mean = red[0] * (1.0f / 768.0f);
    __syncthreads();
    float d0 = v0 - mean, d1 = v1 - mean, d2 = v2 - mean;
    red[tid] = d0 * d0 + d1 * d1 + d2 * d2;
    __syncthreads();
    for (int st = 128; st > 0; st >>= 1) {
        if (tid < st) red[tid] += red[tid + st];
        __syncthreads();
    }
    float rstd = rsqrtf(red[0] * (1.0f / 768.0f) + 1e-6f);
    float* yr = y + (size_t)row * Ch;
    yr[tid]       = d0 * rstd * w[tid]       + b[tid];
    yr[tid + 256] = d1 * rstd * w[tid + 256] + b[tid + 256];
    yr[tid + 512] = d2 * rstd * w[tid + 512] + b[tid + 512];
}

// ---------------------------------------------------------------- mask pooling
__global__ __launch_bounds__(256)
void mask_pool_kernel(const float* __restrict__ mask, float* __restrict__ fg)
{
    int idx = blockIdx.x * 256 + threadIdx.x;   // over B*48*48 = 4608
    if (idx >= Bh * 48 * 48) return;
    int b = idx / (48 * 48);
    int rem = idx % (48 * 48);
    int i = rem / 48, j = rem % 48;
    const float* mb = mask + (size_t)b * 192 * 192;
    float s = 0.0f;
    #pragma unroll
    for (int di = 0; di < 4; ++di)
        #pragma unroll
        for (int dj = 0; dj < 4; ++dj)
            s += mb[(i * 4 + di) * 192 + (j * 4 + dj)];
    fg[idx] = (s * (1.0f / 16.0f) > 0.4f) ? 1.0f : 0.0f;
}

__global__ __launch_bounds__(256)
void mask_win_kernel(const float* __restrict__ fg, float* __restrict__ bgw)
{
    int idx = blockIdx.x * 256 + threadIdx.x;   // over B*6*6 = 72 windows
    if (idx >= Bh * 36) return;
    int b = idx / 36, rem = idx % 36;
    int wi = rem / 6, wj = rem % 6;
    float anybg = 0.0f;
    for (int r = 0; r < 8; ++r)
        for (int c = 0; c < 8; ++c) {
            int n = (wi * 8 + r) * 48 + wj * 8 + c;
            if (fg[b * Lh + n] == 0.0f) anybg = 1.0f;
        }
    bgw[idx] = anybg;
}

// ---------------------------------------------------------------- GEMM
// C[M,N] = act(A[M,K] @ B[K,N] + bias[N]) (+ residual)
#define BM 64
#define BN 64
#define BK 16

__global__ __launch_bounds__(256)
void gemm_kernel(const float* __restrict__ A, const float* __restrict__ B,
                 const float* __restrict__ bias, const float* __restrict__ residual,
                 float* __restrict__ C, int M, int N, int K, int gelu)
{
    __shared__ float As[BK][BM + 4];
    __shared__ float Bs[BK][BN + 4];
    int bm = blockIdx.y * BM;
    int bn = blockIdx.x * BN;
    int tid = threadIdx.x;
    int tx = tid % 16;   // col group
    int ty = tid / 16;   // row group
    float acc[4][4] = {{0.f}};

    for (int k0 = 0; k0 < K; k0 += BK) {
        #pragma unroll
        for (int i = 0; i < 4; ++i) {
            int e = tid + i * 256;
            int m = e / BK, kk = e % BK;
            As[kk][m] = A[(size_t)(bm + m) * K + k0 + kk];
        }
        #pragma unroll
        for (int i = 0; i < 4; ++i) {
            int e = tid + i * 256;
            int kk = e / BN, n = e % BN;
            Bs[kk][n] = B[(size_t)(k0 + kk) * N + bn + n];
        }
        __syncthreads();
        #pragma unroll
        for (int kk = 0; kk < BK; ++kk) {
            float4 a = *(const float4*)&As[kk][ty * 4];
            float4 b4 = *(const float4*)&Bs[kk][tx * 4];
            float av[4] = {a.x, a.y, a.z, a.w};
            float bv[4] = {b4.x, b4.y, b4.z, b4.w};
            #pragma unroll
            for (int i = 0; i < 4; ++i)
                #pragma unroll
                for (int j = 0; j < 4; ++j)
                    acc[i][j] += av[i] * bv[j];
        }
        __syncthreads();
    }

    #pragma unroll
    for (int i = 0; i < 4; ++i) {
        int m = bm + ty * 4 + i;
        float4 out;
        float* o = (float*)&out;
        #pragma unroll
        for (int j = 0; j < 4; ++j) {
            int n = bn + tx * 4 + j;
            float v = acc[i][j] + bias[n];
            if (gelu) v = v * 0.5f * (1.0f + erff(v * 0.70710678f));
            if (residual) v += residual[(size_t)m * N + n];
            o[j] = v;
        }
        *(float4*)&C[(size_t)m * N + bn + tx * 4] = out;
    }
}

// ---------------------------------------------------------------- global attention (flash-tiled)
// block = (b, h, 64-query tile); 256 threads as 16x16 microtile grid.
// LDS: Q^T, K^T (transposed: [d][q]) for GEMM-style S; V row-major; P round-trip.
__global__ __launch_bounds__(256)
void attn_flash_kernel(const float* __restrict__ Q, const float* __restrict__ K,
                       const float* __restrict__ V, const float* __restrict__ fg,
                       float* __restrict__ O)
{
    int qt = blockIdx.x;      // 0..35
    int h  = blockIdx.y;      // 0..11
    int b  = blockIdx.z;      // 0..1
    int tid = threadIdx.x;
    int tx = tid & 15;        // key-col group (S) / d-col group (PV)
    int ty = tid >> 4;        // query-row group

    __shared__ float Qt[64][68];   // [d][q]
    __shared__ float Kt[64][68];   // [d][k]
    __shared__ float Vs[64][68];   // [k][d]
    __shared__ float Ps[64][68];   // [k][q]
    __shared__ float fgs[64];

    // load Q tile, transposed into LDS
    const float* Qbase = Q + ((size_t)(b * Lh + qt * 64)) * Ch + h * 64;
    #pragma unroll
    for (int i = 0; i < 4; ++i) {
        int idx = tid + i * 256;          // float4 index in 64x16
        int row = idx >> 4, c4 = idx & 15;
        float4 v = *(const float4*)(Qbase + (size_t)row * Ch + c4 * 4);
        Qt[c4 * 4 + 0][row] = v.x; Qt[c4 * 4 + 1][row] = v.y;
        Qt[c4 * 4 + 2][row] = v.z; Qt[c4 * 4 + 3][row] = v.w;
    }

    float m_i[4], l_i[4], o_acc[4][4];
    #pragma unroll
    for (int i = 0; i < 4; ++i) {
        m_i[i] = -1e30f; l_i[i] = 0.0f;
        #pragma unroll
        for (int j = 0; j < 4; ++j) o_acc[i][j] = 0.0f;
    }

    for (int kt = 0; kt < 36; ++kt) {
        __syncthreads();   // previous PV reads done -> safe to overwrite K/V
        const float* Kbase = K + ((size_t)(b * Lh + kt * 64)) * Ch + h * 64;
        const float* Vbase = V + ((size_t)(b * Lh + kt * 64)) * Ch + h * 64;
        #pragma unroll
        for (int i = 0; i < 4; ++i) {
            int idx = tid + i * 256;
            int row = idx >> 4, c4 = idx & 15;
            float4 kv = *(const float4*)(Kbase + (size_t)row * Ch + c4 * 4);
            Kt[c4 * 4 + 0][row] = kv.x; Kt[c4 * 4 + 1][row] = kv.y;
            Kt[c4 * 4 + 2][row] = kv.z; Kt[c4 * 4 + 3][row] = kv.w;
            float4 vv = *(const float4*)(Vbase + (size_t)row * Ch + c4 * 4);
            *(float4*)&Vs[row][c4 * 4] = vv;
        }
        if (tid < 64) fgs[tid] = fg[b * Lh + kt * 64 + tid];
        __syncthreads();   // tiles visible

        // S-tile: s[i][j] = sum_d Qt[d][q] * Kt[d][k]
        float s[4][4] = {{0.f}};
        #pragma unroll
        for (int d = 0; d < 64; ++d) {
            float4 qv = *(const float4*)&Qt[d][ty * 4];
            float4 kv = *(const float4*)&Kt[d][tx * 4];
            float qa[4] = {qv.x, qv.y, qv.z, qv.w};
            float ka[4] = {kv.x, kv.y, kv.z, kv.w};
            #pragma unroll
            for (int i = 0; i < 4; ++i)
                #pragma unroll
                for (int j = 0; j < 4; ++j)
                    s[i][j] += qa[i] * ka[j];
        }
        // scale + key mask
        #pragma unroll
        for (int j = 0; j < 4; ++j) {
            float keep = fgs[tx * 4 + j];
            #pragma unroll
            for (int i = 0; i < 4; ++i)
                s[i][j] = (keep != 0.0f) ? s[i][j] * 0.125f : -1e9f;
        }
        // online softmax update (row reductions across tx = lane low nibble)
        #pragma unroll
        for (int i = 0; i < 4; ++i) {
            float tmax = fmaxf(fmaxf(s[i][0], s[i][1]), fmaxf(s[i][2], s[i][3]));
            #pragma unroll
            for (int off = 8; off >= 1; off >>= 1)
                tmax = fmaxf(tmax, __shfl_xor(tmax, off, 64));
            float m_new = fmaxf(m_i[i], tmax);
            float alpha = __expf(m_i[i] - m_new);
            float rsum = 0.0f;
            #pragma unroll
            for (int j = 0; j < 4; ++j) {
                float p = __expf(s[i][j] - m_new);
                s[i][j] = p;
                rsum += p;
            }
            #pragma unroll
            for (int off = 8; off >= 1; off >>= 1)
                rsum += __shfl_xor(rsum, off, 64);
            l_i[i] = l_i[i] * alpha + rsum;
            m_i[i] = m_new;
            #pragma unroll
            for (int j = 0; j < 4; ++j) o_acc[i][j] *= alpha;
        }
        // write P transposed: Ps[k][q]
        #pragma unroll
        for (int i = 0; i < 4; ++i)
            #pragma unroll
            for (int j = 0; j < 4; ++j)
                Ps[tx * 4 + j][ty * 4 + i] = s[i][j];
        __syncthreads();   // P visible

        // PV: o[i][j] += Ps[k][q] * Vs[k][d]
        #pragma unroll
        for (int k = 0; k < 64; ++k) {
            float4 pv = *(const float4*)&Ps[k][ty * 4];
            float4 vv = *(const float4*)&Vs[k][tx * 4];
            float pa[4] = {pv.x, pv.y, pv.z, pv.w};
            float va[4] = {vv.x, vv.y, vv.z, vv.w};
            #pragma unroll
            for (int i = 0; i < 4; ++i)
                #pragma unroll
                for (int j = 0; j < 4; ++j)
                    o_acc[i][j] += pa[i] * va[j];
        }
    }

    // epilogue: divide by l, store coalesced float4
    #pragma unroll
    for (int i = 0; i < 4; ++i) {
        float inv_l = 1.0f / l_i[i];
        int q = qt * 64 + ty * 4 + i;
        float4 out;
        out.x = o_acc[i][0] * inv_l; out.y = o_acc[i][1] * inv_l;
        out.z = o_acc[i][2] * inv_l; out.w = o_acc[i][3] * inv_l;
        *(float4*)&O[((size_t)(b * Lh + q)) * Ch + h * 64 + tx * 4] = out;
    }
}

// ---------------------------------------------------------------- local windowed attention
// wave per (window, h, q); lane = key within window. Output scattered to token layout.
__global__ __launch_bounds__(256)
void attn_local_kernel(const float* __restrict__ Q, const float* __restrict__ K,
                       const float* __restrict__ V, float* __restrict__ O)
{
    int gwave = (blockIdx.x * 256 + threadIdx.x) >> 6;
    int lane = threadIdx.x & 63;
    int wid = threadIdx.x >> 6;
    int qi = gwave & 63;
    int rest = gwave >> 6;
    int h = rest % NHh;
    int win = rest / NHh;           // 0..71
    int b = win / 36;
    int wrem = win % 36;
    int wi = wrem / 6, wj = wrem % 6;
    int qn = (wi * 8 + (qi >> 3)) * 48 + (wj * 8 + (qi & 7));
    int kn = (wi * 8 + (lane >> 3)) * 48 + (wj * 8 + (lane & 7));

    __shared__ float qs[4][64];
    qs[wid][lane] = Q[(size_t)(b * Lh + qn) * Ch + h * 64 + lane];
    __syncthreads();

    const float4* krow = (const float4*)(K + (size_t)(b * Lh + kn) * Ch + h * 64);
    float d = 0.0f;
    #pragma unroll
    for (int i = 0; i < 16; ++i) {
        float4 kv = krow[i];
        float4 qv = *(const float4*)&qs[wid][i * 4];
        d += qv.x * kv.x + qv.y * kv.y + qv.z * kv.z + qv.w * kv.w;
    }
    d *= 0.125f;
    float m = d;
    #pragma unroll
    for (int off = 32; off >= 1; off >>= 1)
        m = fmaxf(m, __shfl_xor(m, off, 64));
    float p = __expf(d - m);
    float lsum = p;
    #pragma unroll
    for (int off = 32; off >= 1; off >>= 1)
        lsum += __shfl_xor(lsum, off, 64);

    const float4* vrow = (const float4*)(V + (size_t)(b * Lh + kn) * Ch + h * 64);
    float res = 0.0f;
    #pragma unroll
    for (int i = 0; i < 16; ++i) {
        float4 vv = vrow[i];
        float t0 = p * vv.x, t1 = p * vv.y, t2 = p * vv.z, t3 = p * vv.w;
        #pragma unroll
        for (int off = 32; off >= 1; off >>= 1) {
            t0 += __shfl_xor(t0, off, 64);
            t1 += __shfl_xor(t1, off, 64);
            t2 += __shfl_xor(t2, off, 64);
            t3 += __shfl_xor(t3, off, 64);
        }
        if (lane == i * 4 + 0) res = t0;
        if (lane == i * 4 + 1) res = t1;
        if (lane == i * 4 + 2) res = t2;
        if (lane == i * 4 + 3) res = t3;
    }
    O[(size_t)(b * Lh + qn) * Ch + h * 64 + lane] = res / lsum;
}

// ---------------------------------------------------------------- scatter + residual
__global__ __launch_bounds__(256)
void scatter_kernel(const float* __restrict__ x, const float* __restrict__ gout,
                    const float* __restrict__ lout, const float* __restrict__ fg,
                    const float* __restrict__ bgw, float* __restrict__ x1)
{
    int idx = blockIdx.x * 256 + threadIdx.x;   // over B*L*C/4 float4s
    if (idx >= Bh * Lh * Ch / 4) return;
    int token = idx / (Ch / 4);
    int b = token / Lh, n = token % Lh;
    int i = n / 48, j = n % 48;
    int win = b * 36 + (i / 8) * 6 + (j / 8);
    float4 xv = ((const float4*)x)[idx];
    float4 sel;
    if (fg[token] != 0.0f)          sel = ((const float4*)gout)[idx];
    else if (bgw[win] != 0.0f)      sel = ((const float4*)lout)[idx];
    else                            sel = make_float4(0.f, 0.f, 0.f, 0.f);
    float4 out;
    out.x = xv.x + sel.x; out.y = xv.y + sel.y;
    out.z = xv.z + sel.z; out.w = xv.w + sel.w;
    ((float4*)x1)[idx] = out;
}

// ---------------------------------------------------------------- launch
extern "C" void kernel_launch(void* const* d_in, const int* in_sizes, int n_in,
                              void* d_out, int out_size, void* d_ws, size_t ws_size,
                              hipStream_t stream)
{
    const float* x       = (const float*)d_in[0];
    const float* mask    = (const float*)d_in[1];
    const float* w_qkv_g = (const float*)d_in[2];
    const float* b_qkv_g = (const float*)d_in[3];
    const float* w_o_g   = (const float*)d_in[4];
    const float* b_o_g   = (const float*)d_in[5];
    const float* w_qkv_l = (const float*)d_in[6];
    const float* b_qkv_l = (const float*)d_in[7];
    const float* w_o_l   = (const float*)d_in[8];
    const float* b_o_l   = (const float*)d_in[9];
    const float* ln1_w   = (const float*)d_in[10];
    const float* ln1_b   = (const float*)d_in[11];
    const float* ln2_w   = (const float*)d_in[12];
    const float* ln2_b   = (const float*)d_in[13];
    const float* w_fc1   = (const float*)d_in[14];
    const float* b_fc1   = (const float*)d_in[15];
    const float* w_fc2   = (const float*)d_in[16];
    const float* b_fc2   = (const float*)d_in[17];
    float* out = (float*)d_out;

    const size_t U = (size_t)Bh * Lh * Ch;   // 3,538,944 floats
    float* ws   = (float*)d_ws;
    float* xn   = ws;            // U   (reused as h1 after LN2)
    float* qkv  = ws + U;        // 3U  (q,k,v; reused for mid together with ctx)
    float* ctx  = ws + 4 * U;    // U
    float* gout = ws + 5 * U;    // U
    float* lout = ws + 6 * U;    // U
    float* x1   = ws + 7 * U;    // U
    float* fg   = ws + 8 * U;    // 4608
    float* bgw  = fg + Bh * Lh;  // 72
    float* mid  = qkv;           // 4608*3072 = 4U, spans qkv+ctx

    const int Mrows = Bh * Lh;   // 4608
    dim3 blk(256);

    // LN1
    layernorm_kernel<<<Mrows, blk, 0, stream>>>(x, ln1_w, ln1_b, xn);
    // masks
    mask_pool_kernel<<<(Bh * 48 * 48 + 255) / 256, blk, 0, stream>>>(mask, fg);
    mask_win_kernel<<<1, blk, 0, stream>>>(fg, bgw);

    // QKV (global)
    for (int t = 0; t < 3; ++t)
        gemm_kernel<<<dim3(Ch / BN, Mrows / BM), blk, 0, stream>>>(
            xn, w_qkv_g + (size_t)t * Ch * Ch, b_qkv_g + t * Ch, nullptr,
            qkv + t * U, Mrows, Ch, Ch, 0);
    // global attention (flash-tiled)
    attn_flash_kernel<<<dim3(36, NHh, Bh), blk, 0, stream>>>(
        qkv, qkv + U, qkv + 2 * U, fg, ctx);
    gemm_kernel<<<dim3(Ch / BN, Mrows / BM), blk, 0, stream>>>(
        ctx, w_o_g, b_o_g, nullptr, gout, Mrows, Ch, Ch, 0);

    // QKV (local) — reuse qkv buffers
    for (int t = 0; t < 3; ++t)
        gemm_kernel<<<dim3(Ch / BN, Mrows / BM), blk, 0, stream>>>(
            xn, w_qkv_l + (size_t)t * Ch * Ch, b_qkv_l + t * Ch, nullptr,
            qkv + t * U, Mrows, Ch, Ch, 0);
    // local attention
    attn_local_kernel<<<(Bh * 36 * NHh * 64) / 4, blk, 0, stream>>>(
        qkv, qkv + U, qkv + 2 * U, ctx);
    gemm_kernel<<<dim3(Ch / BN, Mrows / BM), blk, 0, stream>>>(
        ctx, w_o_l, b_o_l, nullptr, lout, Mrows, Ch, Ch, 0);

    // scatter + residual -> x1
    scatter_kernel<<<(Bh * Lh * Ch / 4 + 255) / 256, blk, 0, stream>>>(
        x, gout, lout, fg, bgw, x1);

    // LN2 -> h (reuse xn)
    layernorm_kernel<<<Mrows, blk, 0, stream>>>(x1, ln2_w, ln2_b, xn);

    // MLP
    gemm_kernel<<<dim3(3072 / BN, Mrows / BM), blk, 0, stream>>>(
        xn, w_fc1, b_fc1, nullptr, mid, Mrows, 3072, Ch, 1);
    gemm_kernel<<<dim3(Ch / BN, Mrows / BM), blk, 0, stream>>>(
        mid, w_fc2, b_fc2, x1, out, Mrows, Ch, 3072, 0);
}

// Round 3
// 729.172 us; speedup vs baseline: 12.3387x; 5.0446x over previous
//
#include <hip/hip_runtime.h>
#include <math.h>

#define Lh 2304
#define Ch 768
#define NHh 12
#define Bh 2

typedef unsigned short ushort_t;
typedef unsigned int uint_t;
typedef __attribute__((ext_vector_type(8))) short bf16x8;
typedef __attribute__((ext_vector_type(4))) float f32x4;
#define MFMA16(a, b, c) __builtin_amdgcn_mfma_f32_16x16x32_bf16(a, b, c, 0, 0, 0)

__device__ __forceinline__ ushort_t f2bf(float f) {
    union { float f; uint_t u; } v; v.f = f;
    uint_t u = v.u + 0x7fffu + ((v.u >> 16) & 1u);   // RNE
    return (ushort_t)(u >> 16);
}

// ---------------------------------------------------------------- layernorm (fp32 in, bf16 out)
__global__ __launch_bounds__(256)
void layernorm_bf16_kernel(const float* __restrict__ x, const float* __restrict__ w,
                           const float* __restrict__ b, ushort_t* __restrict__ y)
{
    int row = blockIdx.x;
    int tid = threadIdx.x;
    const float* xr = x + (size_t)row * Ch;
    float v0 = xr[tid], v1 = xr[tid + 256], v2 = xr[tid + 512];
    __shared__ float red[256];
    red[tid] = v0 + v1 + v2;
    __syncthreads();
    for (int st = 128; st > 0; st >>= 1) {
        if (tid < st) red[tid] += red[tid + st];
        __syncthreads();
    }
    float mean = red[0] * (1.0f / 768.0f);
    __syncthreads();
    float d0 = v0 - mean, d1 = v1 - mean, d2 = v2 - mean;
    red[tid] = d0 * d0 + d1 * d1 + d2 * d2;
    __syncthreads();
    for (int st = 128; st > 0; st >>= 1) {
        if (tid < st) red[tid] += red[tid + st];
        __syncthreads();
    }
    float rstd = rsqrtf(red[0] * (1.0f / 768.0f) + 1e-6f);
    ushort_t* yr = y + (size_t)row * Ch;
    yr[tid]       = f2bf(d0 * rstd * w[tid]       + b[tid]);
    yr[tid + 256] = f2bf(d1 * rstd * w[tid + 256] + b[tid + 256]);
    yr[tid + 512] = f2bf(d2 * rstd * w[tid + 512] + b[tid + 512]);
}

// ---------------------------------------------------------------- mask pooling
__global__ __launch_bounds__(256)
void mask_pool_kernel(const float* __restrict__ mask, float* __restrict__ fg)
{
    int idx = blockIdx.x * 256 + threadIdx.x;
    if (idx >= Bh * 48 * 48) return;
    int b = idx / (48 * 48);
    int rem = idx % (48 * 48);
    int i = rem / 48, j = rem % 48;
    const float* mb = mask + (size_t)b * 192 * 192;
    float s = 0.0f;
    #pragma unroll
    for (int di = 0; di < 4; ++di)
        #pragma unroll
        for (int dj = 0; dj < 4; ++dj)
            s += mb[(i * 4 + di) * 192 + (j * 4 + dj)];
    fg[idx] = (s * (1.0f / 16.0f) > 0.4f) ? 1.0f : 0.0f;
}

__global__ __launch_bounds__(256)
void mask_win_kernel(const float* __restrict__ fg, float* __restrict__ bgw)
{
    int idx = blockIdx.x * 256 + threadIdx.x;
    if (idx >= Bh * 36) return;
    int b = idx / 36, rem = idx % 36;
    int wi = rem / 6, wj = rem % 6;
    float anybg = 0.0f;
    for (int r = 0; r < 8; ++r)
        for (int c = 0; c < 8; ++c) {
            int n = (wi * 8 + r) * 48 + wj * 8 + c;
            if (fg[b * Lh + n] == 0.0f) anybg = 1.0f;
        }
    bgw[idx] = anybg;
}

// ---------------------------------------------------------------- weight cast+transpose: W[K][N] f32 -> Wt[N][K] bf16
__global__ __launch_bounds__(256)
void transpose_cast_kernel(const float* __restrict__ W, ushort_t* __restrict__ Wt,
                           int K, int N)
{
    int n0 = blockIdx.x * 64;
    int k0 = blockIdx.y * 64;
    int tid = threadIdx.x;
    __shared__ float T[64][65];
    #pragma unroll
    for (int i = 0; i < 16; ++i) {
        int lin = i * 256 + tid;
        int r = lin >> 6, c = lin & 63;            // r: k-local, c: n-local
        T[r][c] = W[(size_t)(k0 + r) * N + n0 + c];
    }
    __syncthreads();
    #pragma unroll
    for (int i = 0; i < 16; ++i) {
        int lin = i * 256 + tid;
        int r = lin >> 6, c = lin & 63;            // r: n-local, c: k-local
        Wt[(size_t)(n0 + r) * K + k0 + c] = f2bf(T[c][r]);
    }
}

// ---------------------------------------------------------------- bf16 MFMA GEMM
// C[M,N] = act(A[M,K] @ Bt[N,K]^T + bias) (+residual). flags: 1=gelu, 2=bf16 out
__global__ __launch_bounds__(256)
void gemm_bf16_kernel(const ushort_t* __restrict__ A, const ushort_t* __restrict__ Bt,
                      const float* __restrict__ bias, const float* __restrict__ residual,
                      void* __restrict__ C, int M, int N, int K, int flags)
{
    __shared__ ushort_t As[128][40];
    __shared__ ushort_t Bs[128][40];
    int bm = blockIdx.y * 128;
    int bn = blockIdx.x * 128;
    int tid = threadIdx.x;
    int lane = tid & 63;
    int wave = tid >> 6;
    int wm = wave >> 1, wn = wave & 1;
    int quad = lane >> 4, l15 = lane & 15;

    f32x4 acc[4][4];
    #pragma unroll
    for (int i = 0; i < 4; ++i)
        #pragma unroll
        for (int j = 0; j < 4; ++j)
            acc[i][j] = (f32x4){0.f, 0.f, 0.f, 0.f};

    for (int k0 = 0; k0 < K; k0 += 32) {
        #pragma unroll
        for (int it = 0; it < 2; ++it) {
            int e = tid + it * 256;
            int row = e >> 2, g = e & 3;
            *(uint4*)&As[row][g * 8] = *(const uint4*)(A + (size_t)(bm + row) * K + k0 + g * 8);
            *(uint4*)&Bs[row][g * 8] = *(const uint4*)(Bt + (size_t)(bn + row) * K + k0 + g * 8);
        }
        __syncthreads();
        bf16x8 af[4], bf[4];
        #pragma unroll
        for (int i = 0; i < 4; ++i)
            af[i] = *(const bf16x8*)&As[wm * 64 + i * 16 + l15][quad * 8];
        #pragma unroll
        for (int j = 0; j < 4; ++j)
            bf[j] = *(const bf16x8*)&Bs[wn * 64 + j * 16 + l15][quad * 8];
        #pragma unroll
        for (int i = 0; i < 4; ++i)
            #pragma unroll
            for (int j = 0; j < 4; ++j)
                acc[i][j] = MFMA16(af[i], bf[j], acc[i][j]);
        __syncthreads();
    }

    #pragma unroll
    for (int j = 0; j < 4; ++j) {
        int col = bn + wn * 64 + j * 16 + l15;
        float bia = bias[col];
        #pragma unroll
        for (int i = 0; i < 4; ++i) {
            int row_base = bm + wm * 64 + i * 16 + quad * 4;
            #pragma unroll
            for (int r = 0; r < 4; ++r) {
                int row = row_base + r;
                float v = acc[i][j][r] + bia;
                if (flags & 1) v = v * 0.5f * (1.0f + erff(v * 0.70710678f));
                if (residual) v += residual[(size_t)row * N + col];
                if (flags & 2) ((ushort_t*)C)[(size_t)row * N + col] = f2bf(v);
                else           ((float*)C)[(size_t)row * N + col] = v;
            }
        }
    }
}

// ---------------------------------------------------------------- MFMA flash attention
// mode 0: global, 36 key tiles, fg key mask. mode 1: local window (1 key tile = own window).
// grid (36, NH, B); 4 waves; wave w owns q rows [w*16, w*16+16) of the 64-token tile.
__global__ __launch_bounds__(256)
void attn_mfma_kernel(const ushort_t* __restrict__ Q, const ushort_t* __restrict__ K,
                      const ushort_t* __restrict__ V, const float* __restrict__ fg,
                      ushort_t* __restrict__ O, int mode)
{
    int tile = blockIdx.x;
    int h = blockIdx.y;
    int b = blockIdx.z;
    int tid = threadIdx.x;
    int lane = tid & 63;
    int wave = tid >> 6;
    int quad = lane >> 4, l15 = lane & 15;
    int q0 = wave * 16;
    int wi = tile / 6, wj = tile % 6;

    __shared__ ushort_t Qs[64][72];
    __shared__ ushort_t Ks[64][72];
    __shared__ ushort_t Vt[64][72];
    __shared__ ushort_t Ps[64][72];
    __shared__ float fgs[64];

    // stage Q (token-mapped rows)
    #pragma unroll
    for (int it = 0; it < 2; ++it) {
        int e = tid + it * 256;
        int row = e >> 3, g = e & 7;
        int tok = mode ? ((wi * 8 + (row >> 3)) * 48 + wj * 8 + (row & 7)) : tile * 64 + row;
        *(uint4*)&Qs[row][g * 8] = *(const uint4*)(Q + (size_t)(b * Lh + tok) * Ch + h * 64 + g * 8);
    }

    float m_i[4], l_i[4];
    f32x4 o_acc[4];
    #pragma unroll
    for (int r = 0; r < 4; ++r) { m_i[r] = -1e30f; l_i[r] = 0.0f; }
    #pragma unroll
    for (int t4 = 0; t4 < 4; ++t4) o_acc[t4] = (f32x4){0.f, 0.f, 0.f, 0.f};

    int nkt = mode ? 1 : 36;
    for (int kt = 0; kt < nkt; ++kt) {
        __syncthreads();
        #pragma unroll
        for (int it = 0; it < 2; ++it) {
            int e = tid + it * 256;
            int row = e >> 3, g = e & 7;
            int tok = mode ? ((wi * 8 + (row >> 3)) * 48 + wj * 8 + (row & 7)) : kt * 64 + row;
            *(uint4*)&Ks[row][g * 8] = *(const uint4*)(K + (size_t)(b * Lh + tok) * Ch + h * 64 + g * 8);
            union { uint4 raw; ushort_t us[8]; } vv;
            vv.raw = *(const uint4*)(V + (size_t)(b * Lh + tok) * Ch + h * 64 + g * 8);
            #pragma unroll
            for (int j = 0; j < 8; ++j) Vt[g * 8 + j][row] = vv.us[j];
        }
        if (!mode && tid < 64) fgs[tid] = fg[b * Lh + kt * 64 + tid];
        __syncthreads();

        // S = Q K^T (per-wave 16x64)
        f32x4 s4[4];
        #pragma unroll
        for (int j4 = 0; j4 < 4; ++j4) s4[j4] = (f32x4){0.f, 0.f, 0.f, 0.f};
        #pragma unroll
        for (int step = 0; step < 2; ++step) {
            bf16x8 a = *(const bf16x8*)&Qs[q0 + l15][step * 32 + quad * 8];
            #pragma unroll
            for (int j4 = 0; j4 < 4; ++j4) {
                bf16x8 bk = *(const bf16x8*)&Ks[j4 * 16 + l15][step * 32 + quad * 8];
                s4[j4] = MFMA16(a, bk, s4[j4]);
            }
        }
        // scale + key mask
        #pragma unroll
        for (int j4 = 0; j4 < 4; ++j4) {
            float keep = mode ? 1.0f : fgs[j4 * 16 + l15];
            #pragma unroll
            for (int r = 0; r < 4; ++r)
                s4[j4][r] = (keep != 0.0f) ? s4[j4][r] * 0.125f : -1e9f;
        }
        // online softmax per q row r (reduce across 16-lane groups)
        #pragma unroll
        for (int r = 0; r < 4; ++r) {
            float mx = fmaxf(fmaxf(s4[0][r], s4[1][r]), fmaxf(s4[2][r], s4[3][r]));
            #pragma unroll
            for (int off = 8; off >= 1; off >>= 1)
                mx = fmaxf(mx, __shfl_xor(mx, off, 64));
            float m_new = fmaxf(m_i[r], mx);
            float alpha = __expf(m_i[r] - m_new);
            float rs = 0.0f;
            #pragma unroll
            for (int j4 = 0; j4 < 4; ++j4) {
                float p = __expf(s4[j4][r] - m_new);
                s4[j4][r] = p;
                rs += p;
            }
            #pragma unroll
            for (int off = 8; off >= 1; off >>= 1)
                rs += __shfl_xor(rs, off, 64);
            l_i[r] = l_i[r] * alpha + rs;
            m_i[r] = m_new;
            #pragma unroll
            for (int t4 = 0; t4 < 4; ++t4) o_acc[t4][r] *= alpha;
        }
        // P (C-layout) -> LDS, own 16-row stripe
        #pragma unroll
        for (int j4 = 0; j4 < 4; ++j4)
            #pragma unroll
            for (int r = 0; r < 4; ++r)
                Ps[q0 + quad * 4 + r][j4 * 16 + l15] = f2bf(s4[j4][r]);
        // PV (reads own stripe; in-wave lgkmcnt ordering suffices)
        #pragma unroll
        for (int step = 0; step < 2; ++step) {
            bf16x8 a = *(const bf16x8*)&Ps[q0 + l15][step * 32 + quad * 8];
            #pragma unroll
            for (int t4 = 0; t4 < 4; ++t4) {
                bf16x8 bv = *(const bf16x8*)&Vt[t4 * 16 + l15][step * 32 + quad * 8];
                o_acc[t4] = MFMA16(a, bv, o_acc[t4]);
            }
        }
    }

    // epilogue
    #pragma unroll
    for (int r = 0; r < 4; ++r) {
        float inv = 1.0f / l_i[r];
        int i = q0 + quad * 4 + r;
        int tok = mode ? ((wi * 8 + (i >> 3)) * 48 + wj * 8 + (i & 7)) : tile * 64 + i;
        #pragma unroll
        for (int t4 = 0; t4 < 4; ++t4)
            O[(size_t)(b * Lh + tok) * Ch + h * 64 + t4 * 16 + l15] = f2bf(o_acc[t4][r] * inv);
    }
}

// ---------------------------------------------------------------- scatter + residual (fp32)
__global__ __launch_bounds__(256)
void scatter_kernel(const float* __restrict__ x, const float* __restrict__ gout,
                    const float* __restrict__ lout, const float* __restrict__ fg,
                    const float* __restrict__ bgw, float* __restrict__ x1)
{
    int idx = blockIdx.x * 256 + threadIdx.x;
    if (idx >= Bh * Lh * Ch / 4) return;
    int token = idx / (Ch / 4);
    int b = token / Lh, n = token % Lh;
    int i = n / 48, j = n % 48;
    int win = b * 36 + (i / 8) * 6 + (j / 8);
    float4 xv = ((const float4*)x)[idx];
    float4 sel;
    if (fg[token] != 0.0f)          sel = ((const float4*)gout)[idx];
    else if (bgw[win] != 0.0f)      sel = ((const float4*)lout)[idx];
    else                            sel = make_float4(0.f, 0.f, 0.f, 0.f);
    float4 out;
    out.x = xv.x + sel.x; out.y = xv.y + sel.y;
    out.z = xv.z + sel.z; out.w = xv.w + sel.w;
    ((float4*)x1)[idx] = out;
}

// ---------------------------------------------------------------- launch
extern "C" void kernel_launch(void* const* d_in, const int* in_sizes, int n_in,
                              void* d_out, int out_size, void* d_ws, size_t ws_size,
                              hipStream_t stream)
{
    const float* x       = (const float*)d_in[0];
    const float* mask    = (const float*)d_in[1];
    const float* w_qkv_g = (const float*)d_in[2];
    const float* b_qkv_g = (const float*)d_in[3];
    const float* w_o_g   = (const float*)d_in[4];
    const float* b_o_g   = (const float*)d_in[5];
    const float* w_qkv_l = (const float*)d_in[6];
    const float* b_qkv_l = (const float*)d_in[7];
    const float* w_o_l   = (const float*)d_in[8];
    const float* b_o_l   = (const float*)d_in[9];
    const float* ln1_w   = (const float*)d_in[10];
    const float* ln1_b   = (const float*)d_in[11];
    const float* ln2_w   = (const float*)d_in[12];
    const float* ln2_b   = (const float*)d_in[13];
    const float* w_fc1   = (const float*)d_in[14];
    const float* b_fc1   = (const float*)d_in[15];
    const float* w_fc2   = (const float*)d_in[16];
    const float* b_fc2   = (const float*)d_in[17];
    float* out = (float*)d_out;

    const size_t U = (size_t)Bh * Lh * Ch;           // 3,538,944
    char* p = (char*)d_ws;
    ushort_t* qkvb = (ushort_t*)p;        p += 3 * U * 2;       // bf16 q,k,v
    ushort_t* ctxb = (ushort_t*)p;        p += U * 2;           // bf16 attn ctx
    ushort_t* midb = qkvb;                                      // bf16 4608x3072 aliases qkv+ctx
    ushort_t* xnb  = (ushort_t*)p;        p += U * 2;           // bf16 LN out
    float*    gout = (float*)p;           p += U * 4;
    float*    lout = (float*)p;           p += U * 4;
    float*    x1   = (float*)p;           p += U * 4;
    ushort_t* wt   = (ushort_t*)p;        p += (size_t)9437184 * 2;
    float*    fg   = (float*)p;           p += Bh * Lh * 4;
    float*    bgw  = (float*)p;

    ushort_t* wt_qkv_g = wt;                     // 3 x [768][768]
    ushort_t* wt_o_g   = wt + 1769472;           // [768][768]
    ushort_t* wt_qkv_l = wt + 2359296;           // 3 x [768][768]
    ushort_t* wt_o_l   = wt + 4128768;           // [768][768]
    ushort_t* wt_fc1   = wt + 4718592;           // [3072][768]
    ushort_t* wt_fc2   = wt + 7077888;           // [768][3072]

    const int Mrows = Bh * Lh;                   // 4608
    dim3 blk(256);

    // weight cast+transpose
    for (int t = 0; t < 3; ++t) {
        transpose_cast_kernel<<<dim3(12, 12), blk, 0, stream>>>(
            w_qkv_g + (size_t)t * Ch * Ch, wt_qkv_g + (size_t)t * Ch * Ch, Ch, Ch);
        transpose_cast_kernel<<<dim3(12, 12), blk, 0, stream>>>(
            w_qkv_l + (size_t)t * Ch * Ch, wt_qkv_l + (size_t)t * Ch * Ch, Ch, Ch);
    }
    transpose_cast_kernel<<<dim3(12, 12), blk, 0, stream>>>(w_o_g, wt_o_g, Ch, Ch);
    transpose_cast_kernel<<<dim3(12, 12), blk, 0, stream>>>(w_o_l, wt_o_l, Ch, Ch);
    transpose_cast_kernel<<<dim3(48, 12), blk, 0, stream>>>(w_fc1, wt_fc1, Ch, 3072);
    transpose_cast_kernel<<<dim3(12, 48), blk, 0, stream>>>(w_fc2, wt_fc2, 3072, Ch);

    // LN1 -> bf16
    layernorm_bf16_kernel<<<Mrows, blk, 0, stream>>>(x, ln1_w, ln1_b, xnb);
    // masks
    mask_pool_kernel<<<(Bh * 48 * 48 + 255) / 256, blk, 0, stream>>>(mask, fg);
    mask_win_kernel<<<1, blk, 0, stream>>>(fg, bgw);

    // global branch
    for (int t = 0; t < 3; ++t)
        gemm_bf16_kernel<<<dim3(Ch / 128, Mrows / 128), blk, 0, stream>>>(
            xnb, wt_qkv_g + (size_t)t * Ch * Ch, b_qkv_g + t * Ch, nullptr,
            qkvb + t * U, Mrows, Ch, Ch, 2);
    attn_mfma_kernel<<<dim3(36, NHh, Bh), blk, 0, stream>>>(
        qkvb, qkvb + U, qkvb + 2 * U, fg, ctxb, 0);
    gemm_bf16_kernel<<<dim3(Ch / 128, Mrows / 128), blk, 0, stream>>>(
        ctxb, wt_o_g, b_o_g, nullptr, gout, Mrows, Ch, Ch, 0);

    // local branch
    for (int t = 0; t < 3; ++t)
        gemm_bf16_kernel<<<dim3(Ch / 128, Mrows / 128), blk, 0, stream>>>(
            xnb, wt_qkv_l + (size_t)t * Ch * Ch, b_qkv_l + t * Ch, nullptr,
            qkvb + t * U, Mrows, Ch, Ch, 2);
    attn_mfma_kernel<<<dim3(36, NHh, Bh), blk, 0, stream>>>(
        qkvb, qkvb + U, qkvb + 2 * U, fg, ctxb, 1);
    gemm_bf16_kernel<<<dim3(Ch / 128, Mrows / 128), blk, 0, stream>>>(
        ctxb, wt_o_l, b_o_l, nullptr, lout, Mrows, Ch, Ch, 0);

    // scatter + residual
    scatter_kernel<<<(Bh * Lh * Ch / 4 + 255) / 256, blk, 0, stream>>>(
        x, gout, lout, fg, bgw, x1);

    // LN2 -> bf16
    layernorm_bf16_kernel<<<Mrows, blk, 0, stream>>>(x1, ln2_w, ln2_b, xnb);

    // MLP
    gemm_bf16_kernel<<<dim3(3072 / 128, Mrows / 128), blk, 0, stream>>>(
        xnb, wt_fc1, b_fc1, nullptr, midb, Mrows, 3072, Ch, 1 | 2);
    gemm_bf16_kernel<<<dim3(Ch / 128, Mrows / 128), blk, 0, stream>>>(
        midb, wt_fc2, b_fc2, x1, out, Mrows, Ch, 3072, 0);
}

// Round 4
// 592.014 us; speedup vs baseline: 15.1973x; 1.2317x over previous
//
#include <hip/hip_runtime.h>
#include <math.h>

#define Lh 2304
#define Ch 768
#define NHh 12
#define Bh 2
#define QS 2304   // row stride of fused qkv activation buffer

typedef unsigned short ushort_t;
typedef unsigned int uint_t;
typedef __attribute__((ext_vector_type(8))) short bf16x8;
typedef __attribute__((ext_vector_type(4))) float f32x4;
#define MFMA16(a, b, c) __builtin_amdgcn_mfma_f32_16x16x32_bf16(a, b, c, 0, 0, 0)

__device__ __forceinline__ ushort_t f2bf(float f) {
    union { float f; uint_t u; } v; v.f = f;
    uint_t u = v.u + 0x7fffu + ((v.u >> 16) & 1u);   // RNE
    return (ushort_t)(u >> 16);
}

// ---------------------------------------------------------------- layernorm (fp32 in, bf16 out)
__global__ __launch_bounds__(256)
void layernorm_bf16_kernel(const float* __restrict__ x, const float* __restrict__ w,
                           const float* __restrict__ b, ushort_t* __restrict__ y)
{
    int row = blockIdx.x;
    int tid = threadIdx.x;
    const float* xr = x + (size_t)row * Ch;
    float v0 = xr[tid], v1 = xr[tid + 256], v2 = xr[tid + 512];
    __shared__ float red[256];
    red[tid] = v0 + v1 + v2;
    __syncthreads();
    for (int st = 128; st > 0; st >>= 1) {
        if (tid < st) red[tid] += red[tid + st];
        __syncthreads();
    }
    float mean = red[0] * (1.0f / 768.0f);
    __syncthreads();
    float d0 = v0 - mean, d1 = v1 - mean, d2 = v2 - mean;
    red[tid] = d0 * d0 + d1 * d1 + d2 * d2;
    __syncthreads();
    for (int st = 128; st > 0; st >>= 1) {
        if (tid < st) red[tid] += red[tid + st];
        __syncthreads();
    }
    float rstd = rsqrtf(red[0] * (1.0f / 768.0f) + 1e-6f);
    ushort_t* yr = y + (size_t)row * Ch;
    yr[tid]       = f2bf(d0 * rstd * w[tid]       + b[tid]);
    yr[tid + 256] = f2bf(d1 * rstd * w[tid + 256] + b[tid + 256]);
    yr[tid + 512] = f2bf(d2 * rstd * w[tid + 512] + b[tid + 512]);
}

// ---------------------------------------------------------------- mask pooling
__global__ __launch_bounds__(256)
void mask_pool_kernel(const float* __restrict__ mask, float* __restrict__ fg)
{
    int idx = blockIdx.x * 256 + threadIdx.x;
    if (idx >= Bh * 48 * 48) return;
    int b = idx / (48 * 48);
    int rem = idx % (48 * 48);
    int i = rem / 48, j = rem % 48;
    const float* mb = mask + (size_t)b * 192 * 192;
    float s = 0.0f;
    #pragma unroll
    for (int di = 0; di < 4; ++di)
        #pragma unroll
        for (int dj = 0; dj < 4; ++dj)
            s += mb[(i * 4 + di) * 192 + (j * 4 + dj)];
    fg[idx] = (s * (1.0f / 16.0f) > 0.4f) ? 1.0f : 0.0f;
}

__global__ __launch_bounds__(256)
void mask_win_kernel(const float* __restrict__ fg, float* __restrict__ bgw)
{
    int idx = blockIdx.x * 256 + threadIdx.x;
    if (idx >= Bh * 36) return;
    int b = idx / 36, rem = idx % 36;
    int wi = rem / 6, wj = rem % 6;
    float anybg = 0.0f;
    for (int r = 0; r < 8; ++r)
        for (int c = 0; c < 8; ++c) {
            int n = (wi * 8 + r) * 48 + wj * 8 + c;
            if (fg[b * Lh + n] == 0.0f) anybg = 1.0f;
        }
    bgw[idx] = anybg;
}

// ---------------------------------------------------------------- weight cast+transpose: W[K][N] f32 -> Wt[N][K] bf16
__global__ __launch_bounds__(256)
void transpose_cast_kernel(const float* __restrict__ W, ushort_t* __restrict__ Wt,
                           int K, int N)
{
    int n0 = blockIdx.x * 64;
    int k0 = blockIdx.y * 64;
    int tid = threadIdx.x;
    __shared__ float T[64][65];
    #pragma unroll
    for (int i = 0; i < 16; ++i) {
        int lin = i * 256 + tid;
        int r = lin >> 6, c = lin & 63;
        T[r][c] = W[(size_t)(k0 + r) * N + n0 + c];
    }
    __syncthreads();
    #pragma unroll
    for (int i = 0; i < 16; ++i) {
        int lin = i * 256 + tid;
        int r = lin >> 6, c = lin & 63;
        Wt[(size_t)(n0 + r) * K + k0 + c] = f2bf(T[c][r]);
    }
}

// ---------------------------------------------------------------- bf16 MFMA GEMM
// C[M,N] = act(A[M,K] @ Bt[N,K]^T + bias) [+residual] with optional row-masking.
// flags: 1=gelu, 2=bf16 out, 4=fg-masked add (C=res+fg[row]*v), 8=bg-local masked add
__global__ __launch_bounds__(256)
void gemm_bf16_kernel(const ushort_t* __restrict__ A, const ushort_t* __restrict__ Bt,
                      const float* __restrict__ bias, const float* __restrict__ residual,
                      void* __restrict__ C, int M, int N, int K, int flags,
                      const float* __restrict__ fg, const float* __restrict__ bgw)
{
    __shared__ ushort_t As[128][40];
    __shared__ ushort_t Bs[128][40];
    int bm = blockIdx.y * 128;
    int bn = blockIdx.x * 128;
    int tid = threadIdx.x;
    int lane = tid & 63;
    int wave = tid >> 6;
    int wm = wave >> 1, wn = wave & 1;
    int quad = lane >> 4, l15 = lane & 15;

    f32x4 acc[4][4];
    #pragma unroll
    for (int i = 0; i < 4; ++i)
        #pragma unroll
        for (int j = 0; j < 4; ++j)
            acc[i][j] = (f32x4){0.f, 0.f, 0.f, 0.f};

    for (int k0 = 0; k0 < K; k0 += 32) {
        #pragma unroll
        for (int it = 0; it < 2; ++it) {
            int e = tid + it * 256;
            int row = e >> 2, g = e & 3;
            *(uint4*)&As[row][g * 8] = *(const uint4*)(A + (size_t)(bm + row) * K + k0 + g * 8);
            *(uint4*)&Bs[row][g * 8] = *(const uint4*)(Bt + (size_t)(bn + row) * K + k0 + g * 8);
        }
        __syncthreads();
        bf16x8 af[4], bf[4];
        #pragma unroll
        for (int i = 0; i < 4; ++i)
            af[i] = *(const bf16x8*)&As[wm * 64 + i * 16 + l15][quad * 8];
        #pragma unroll
        for (int j = 0; j < 4; ++j)
            bf[j] = *(const bf16x8*)&Bs[wn * 64 + j * 16 + l15][quad * 8];
        #pragma unroll
        for (int i = 0; i < 4; ++i)
            #pragma unroll
            for (int j = 0; j < 4; ++j)
                acc[i][j] = MFMA16(af[i], bf[j], acc[i][j]);
        __syncthreads();
    }

    float bia[4];
    #pragma unroll
    for (int j = 0; j < 4; ++j) bia[j] = bias[bn + wn * 64 + j * 16 + l15];

    #pragma unroll
    for (int i = 0; i < 4; ++i) {
        #pragma unroll
        for (int r = 0; r < 4; ++r) {
            int row = bm + wm * 64 + i * 16 + quad * 4 + r;
            float keep = 1.0f;
            if (flags & 4) keep = (fg[row] != 0.0f) ? 1.0f : 0.0f;
            if (flags & 8) {
                int bb = (row >= Lh) ? 1 : 0;
                int n = row - bb * Lh;
                int ii = n / 48, jj = n % 48;
                keep = (fg[row] == 0.0f && bgw[bb * 36 + (ii >> 3) * 6 + (jj >> 3)] != 0.0f)
                           ? 1.0f : 0.0f;
            }
            #pragma unroll
            for (int j = 0; j < 4; ++j) {
                int col = bn + wn * 64 + j * 16 + l15;
                float v = acc[i][j][r] + bia[j];
                if (flags & 1) v = v * 0.5f * (1.0f + erff(v * 0.70710678f));
                float o;
                if (flags & (4 | 8)) o = residual[(size_t)row * N + col] + keep * v;
                else if (residual)   o = residual[(size_t)row * N + col] + v;
                else                 o = v;
                if (flags & 2) ((ushort_t*)C)[(size_t)row * N + col] = f2bf(o);
                else           ((float*)C)[(size_t)row * N + col] = o;
            }
        }
    }
}

// ---------------------------------------------------------------- MFMA flash attention (no-max softmax)
// QKV fused buffer [tok][2304] (q|k|v). mode 0: global w/ fg mask; mode 1: local window.
// grid (36, NH, B), 4 waves, wave w owns q rows [w*16, w*16+16).
// Vt is XOR-swizzled: Vt[d][tok ^ ((d>>3)<<3)] -> conflict-free transposed staging.
__global__ __launch_bounds__(256)
void attn_mfma_kernel(const ushort_t* __restrict__ QKV, const float* __restrict__ fg,
                      ushort_t* __restrict__ O, int mode)
{
    int tile = blockIdx.x;
    int h = blockIdx.y;
    int b = blockIdx.z;
    int tid = threadIdx.x;
    int lane = tid & 63;
    int wave = tid >> 6;
    int quad = lane >> 4, l15 = lane & 15;
    int q0 = wave * 16;
    int wi = tile / 6, wj = tile % 6;

    __shared__ ushort_t Qs[64][72];
    __shared__ ushort_t Ks[64][72];
    __shared__ ushort_t Vt[64][72];
    __shared__ ushort_t Ps[64][72];
    __shared__ float fgs[64];

    // stage Q
    #pragma unroll
    for (int it = 0; it < 2; ++it) {
        int e = tid + it * 256;
        int row = e >> 3, g = e & 7;
        int tok = mode ? ((wi * 8 + (row >> 3)) * 48 + wj * 8 + (row & 7)) : tile * 64 + row;
        *(uint4*)&Qs[row][g * 8] = *(const uint4*)(QKV + (size_t)(b * Lh + tok) * QS + h * 64 + g * 8);
    }

    float l_part[4] = {0.f, 0.f, 0.f, 0.f};
    f32x4 o_acc[4];
    #pragma unroll
    for (int t4 = 0; t4 < 4; ++t4) o_acc[t4] = (f32x4){0.f, 0.f, 0.f, 0.f};

    int nkt = mode ? 1 : 36;

    // prefetch tile 0
    uint4 kx[2], vx[2];
    #pragma unroll
    for (int it = 0; it < 2; ++it) {
        int e = tid + it * 256;
        int row = e >> 3, g = e & 7;
        int tok = mode ? ((wi * 8 + (row >> 3)) * 48 + wj * 8 + (row & 7)) : row;
        const ushort_t* base = QKV + (size_t)(b * Lh + tok) * QS + h * 64 + g * 8;
        kx[it] = *(const uint4*)(base + 768);
        vx[it] = *(const uint4*)(base + 1536);
    }
    float fgn = 0.f;
    if (!mode && tid < 64) fgn = fg[b * Lh + tid];

    for (int kt = 0; kt < nkt; ++kt) {
        __syncthreads();   // all waves done reading previous K/V
        #pragma unroll
        for (int it = 0; it < 2; ++it) {
            int e = tid + it * 256;
            int row = e >> 3, g = e & 7;
            *(uint4*)&Ks[row][g * 8] = kx[it];
            union { uint4 raw; ushort_t us[8]; } vv;
            vv.raw = vx[it];
            int col = row ^ (g << 3);
            #pragma unroll
            for (int j = 0; j < 8; ++j) Vt[g * 8 + j][col] = vv.us[j];
        }
        if (!mode && tid < 64) fgs[tid] = (fgn - 1.0f) * 1e9f;   // 0 -> -1e9, 1 -> 0
        __syncthreads();

        // prefetch next tile (global mode only; issues before compute)
        if (kt + 1 < nkt) {
            #pragma unroll
            for (int it = 0; it < 2; ++it) {
                int e = tid + it * 256;
                int row = e >> 3, g = e & 7;
                int tok = (kt + 1) * 64 + row;
                const ushort_t* base = QKV + (size_t)(b * Lh + tok) * QS + h * 64 + g * 8;
                kx[it] = *(const uint4*)(base + 768);
                vx[it] = *(const uint4*)(base + 1536);
            }
            if (tid < 64) fgn = fg[b * Lh + (kt + 1) * 64 + tid];
        }

        // S = Q K^T (per-wave 16x64)
        f32x4 s4[4];
        #pragma unroll
        for (int j4 = 0; j4 < 4; ++j4) s4[j4] = (f32x4){0.f, 0.f, 0.f, 0.f};
        #pragma unroll
        for (int step = 0; step < 2; ++step) {
            bf16x8 a = *(const bf16x8*)&Qs[q0 + l15][step * 32 + quad * 8];
            #pragma unroll
            for (int j4 = 0; j4 < 4; ++j4) {
                bf16x8 bk = *(const bf16x8*)&Ks[j4 * 16 + l15][step * 32 + quad * 8];
                s4[j4] = MFMA16(a, bk, s4[j4]);
            }
        }
        // scale + mask + exp (no running max: scores bounded, fp32 exp safe)
        #pragma unroll
        for (int j4 = 0; j4 < 4; ++j4) {
            float mb = mode ? 0.0f : fgs[j4 * 16 + l15];
            #pragma unroll
            for (int r = 0; r < 4; ++r) {
                float p = __expf(s4[j4][r] * 0.125f + mb);
                s4[j4][r] = p;
                l_part[r] += p;
            }
        }
        // P -> LDS (own 16-row stripe; in-wave ordering suffices)
        #pragma unroll
        for (int j4 = 0; j4 < 4; ++j4)
            #pragma unroll
            for (int r = 0; r < 4; ++r)
                Ps[q0 + quad * 4 + r][j4 * 16 + l15] = f2bf(s4[j4][r]);
        // PV
        #pragma unroll
        for (int step = 0; step < 2; ++step) {
            bf16x8 a = *(const bf16x8*)&Ps[q0 + l15][step * 32 + quad * 8];
            #pragma unroll
            for (int t4 = 0; t4 < 4; ++t4) {
                int dd = t4 * 16 + l15;
                int cb = ((step * 4 + quad) ^ ((dd >> 3) & 7)) * 8;
                bf16x8 bv = *(const bf16x8*)&Vt[dd][cb];
                o_acc[t4] = MFMA16(a, bv, o_acc[t4]);
            }
        }
    }

    // final row-sum reduce across l15 groups
    #pragma unroll
    for (int r = 0; r < 4; ++r) {
        float v = l_part[r];
        #pragma unroll
        for (int off = 8; off >= 1; off >>= 1)
            v += __shfl_xor(v, off, 64);
        l_part[r] = v;
    }

    // epilogue
    #pragma unroll
    for (int r = 0; r < 4; ++r) {
        float inv = 1.0f / l_part[r];
        int i = q0 + quad * 4 + r;
        int tok = mode ? ((wi * 8 + (i >> 3)) * 48 + wj * 8 + (i & 7)) : tile * 64 + i;
        #pragma unroll
        for (int t4 = 0; t4 < 4; ++t4)
            O[(size_t)(b * Lh + tok) * Ch + h * 64 + t4 * 16 + l15] = f2bf(o_acc[t4][r] * inv);
    }
}

// ---------------------------------------------------------------- launch
extern "C" void kernel_launch(void* const* d_in, const int* in_sizes, int n_in,
                              void* d_out, int out_size, void* d_ws, size_t ws_size,
                              hipStream_t stream)
{
    const float* x       = (const float*)d_in[0];
    const float* mask    = (const float*)d_in[1];
    const float* w_qkv_g = (const float*)d_in[2];
    const float* b_qkv_g = (const float*)d_in[3];
    const float* w_o_g   = (const float*)d_in[4];
    const float* b_o_g   = (const float*)d_in[5];
    const float* w_qkv_l = (const float*)d_in[6];
    const float* b_qkv_l = (const float*)d_in[7];
    const float* w_o_l   = (const float*)d_in[8];
    const float* b_o_l   = (const float*)d_in[9];
    const float* ln1_w   = (const float*)d_in[10];
    const float* ln1_b   = (const float*)d_in[11];
    const float* ln2_w   = (const float*)d_in[12];
    const float* ln2_b   = (const float*)d_in[13];
    const float* w_fc1   = (const float*)d_in[14];
    const float* b_fc1   = (const float*)d_in[15];
    const float* w_fc2   = (const float*)d_in[16];
    const float* b_fc2   = (const float*)d_in[17];
    float* out = (float*)d_out;

    const size_t U = (size_t)Bh * Lh * Ch;           // 3,538,944
    char* p = (char*)d_ws;
    ushort_t* qkvb = (ushort_t*)p;        p += 3 * U * 2;   // bf16 [4608][2304] fused q|k|v
    ushort_t* ctxb = (ushort_t*)p;        p += U * 2;       // bf16 attn ctx [4608][768]
    ushort_t* midb = qkvb;                                  // bf16 [4608][3072] aliases qkv+ctx
    ushort_t* xnb  = (ushort_t*)p;        p += U * 2;       // bf16 LN out
    float*    x1   = (float*)p;           p += U * 4;       // fp32 post-attn residual
    ushort_t* wt   = (ushort_t*)p;        p += (size_t)9437184 * 2;
    float*    fg   = (float*)p;           p += Bh * Lh * 4;
    float*    bgw  = (float*)p;

    ushort_t* wt_qkv_g = wt;                     // [2304][768]
    ushort_t* wt_o_g   = wt + 1769472;           // [768][768]
    ushort_t* wt_qkv_l = wt + 2359296;           // [2304][768]
    ushort_t* wt_o_l   = wt + 4128768;           // [768][768]
    ushort_t* wt_fc1   = wt + 4718592;           // [3072][768]
    ushort_t* wt_fc2   = wt + 7077888;           // [768][3072]

    const int Mrows = Bh * Lh;                   // 4608
    dim3 blk(256);

    // weight cast+transpose (each (t,C,C) slice -> rows t*C..t*C+C of concat Bt)
    for (int t = 0; t < 3; ++t) {
        transpose_cast_kernel<<<dim3(12, 12), blk, 0, stream>>>(
            w_qkv_g + (size_t)t * Ch * Ch, wt_qkv_g + (size_t)t * Ch * Ch, Ch, Ch);
        transpose_cast_kernel<<<dim3(12, 12), blk, 0, stream>>>(
            w_qkv_l + (size_t)t * Ch * Ch, wt_qkv_l + (size_t)t * Ch * Ch, Ch, Ch);
    }
    transpose_cast_kernel<<<dim3(12, 12), blk, 0, stream>>>(w_o_g, wt_o_g, Ch, Ch);
    transpose_cast_kernel<<<dim3(12, 12), blk, 0, stream>>>(w_o_l, wt_o_l, Ch, Ch);
    transpose_cast_kernel<<<dim3(48, 12), blk, 0, stream>>>(w_fc1, wt_fc1, Ch, 3072);
    transpose_cast_kernel<<<dim3(12, 48), blk, 0, stream>>>(w_fc2, wt_fc2, 3072, Ch);

    // LN1 -> bf16; masks
    layernorm_bf16_kernel<<<Mrows, blk, 0, stream>>>(x, ln1_w, ln1_b, xnb);
    mask_pool_kernel<<<(Bh * 48 * 48 + 255) / 256, blk, 0, stream>>>(mask, fg);
    mask_win_kernel<<<1, blk, 0, stream>>>(fg, bgw);

    // global branch: fused QKV GEMM (N=2304), attention, masked o-proj into x1
    gemm_bf16_kernel<<<dim3(2304 / 128, Mrows / 128), blk, 0, stream>>>(
        xnb, wt_qkv_g, b_qkv_g, nullptr, qkvb, Mrows, 2304, Ch, 2, nullptr, nullptr);
    attn_mfma_kernel<<<dim3(36, NHh, Bh), blk, 0, stream>>>(qkvb, fg, ctxb, 0);
    gemm_bf16_kernel<<<dim3(Ch / 128, Mrows / 128), blk, 0, stream>>>(
        ctxb, wt_o_g, b_o_g, x, x1, Mrows, Ch, Ch, 4, fg, nullptr);

    // local branch
    gemm_bf16_kernel<<<dim3(2304 / 128, Mrows / 128), blk, 0, stream>>>(
        xnb, wt_qkv_l, b_qkv_l, nullptr, qkvb, Mrows, 2304, Ch, 2, nullptr, nullptr);
    attn_mfma_kernel<<<dim3(36, NHh, Bh), blk, 0, stream>>>(qkvb, fg, ctxb, 1);
    gemm_bf16_kernel<<<dim3(Ch / 128, Mrows / 128), blk, 0, stream>>>(
        ctxb, wt_o_l, b_o_l, x1, x1, Mrows, Ch, Ch, 8, fg, bgw);

    // LN2 -> bf16
    layernorm_bf16_kernel<<<Mrows, blk, 0, stream>>>(x1, ln2_w, ln2_b, xnb);

    // MLP
    gemm_bf16_kernel<<<dim3(3072 / 128, Mrows / 128), blk, 0, stream>>>(
        xnb, wt_fc1, b_fc1, nullptr, midb, Mrows, 3072, Ch, 1 | 2, nullptr, nullptr);
    gemm_bf16_kernel<<<dim3(Ch / 128, Mrows / 128), blk, 0, stream>>>(
        midb, wt_fc2, b_fc2, x1, out, Mrows, Ch, 3072, 0, nullptr, nullptr);
}